// Round 1
// baseline (252.215 us; speedup 1.0000x reference)
//
#include <hip/hip_runtime.h>
#include <math.h>

// Problem constants (fixed by reference setup_inputs)
#define BATCH   32
#define CCH     128      // channels
#define HWTOK   4096     // H*W tokens per batch
#define MROWS   512      // memory rows
#define TTILE   64       // tokens per block
#define RCHUNK  64       // memory rows per LDS chunk
#define NCHUNK  (MROWS / RCHUNK)   // 8
#define MS_STRIDE 132    // padded row stride (floats) for ms tile
#define THREADS 256

typedef float f4 __attribute__((ext_vector_type(4)));

// Kernel A: reciprocal L2 norms of memory rows -> d_ws (512 floats)
__global__ __launch_bounds__(64) void rinv_kernel(const float* __restrict__ mem,
                                                  float* __restrict__ rinv) {
    int r = blockIdx.x * 64 + threadIdx.x;
    if (r >= MROWS) return;
    const float* row = mem + (size_t)r * CCH;
    float s = 0.f;
    #pragma unroll 8
    for (int c = 0; c < CCH; ++c) { float v = row[c]; s += v * v; }
    float n = sqrtf(s);
    rinv[r] = 1.0f / fmaxf(n, 1e-12f);
}

// Kernel B: per 64-token tile: sim = dot(x, m)*rinv_m, running (max, argmax)
// over 512 rows, then masked gather of raw memory rows into [B,C,H,W] output.
__global__ __launch_bounds__(THREADS) void hardmem_kernel(
    const float* __restrict__ x, const float* __restrict__ mem,
    const float* __restrict__ rinv_g, float* __restrict__ out)
{
    __shared__ __align__(16) float xs[CCH * TTILE];          // [c][t]   32 KB
    __shared__ __align__(16) float ms[RCHUNK * MS_STRIDE];   // [row][c] 33 KB (padded)
    __shared__ float rinvs[MROWS];                            // 2 KB
    __shared__ float redv[TTILE * 16];                        // 4 KB
    __shared__ int   redi[TTILE * 16];                        // 4 KB
    __shared__ float fmask[TTILE];
    __shared__ int   fidx[TTILE];

    const int tid = threadIdx.x;
    const int b   = blockIdx.x >> 6;           // / 64 tiles per batch
    const int t0  = (blockIdx.x & 63) * TTILE; // token offset within batch
    const float* xb = x + (size_t)b * CCH * HWTOK + t0;

    // ---- stage x tile: global [c][t] (coalesced float4) -> LDS xs[c][t]
    #pragma unroll
    for (int k = 0; k < 8; ++k) {
        int l4 = tid + k * THREADS;            // 0..2047 float4s
        int c = l4 >> 4, t4 = l4 & 15;
        f4 v = *reinterpret_cast<const f4*>(xb + (size_t)c * HWTOK + t4 * 4);
        *reinterpret_cast<f4*>(&xs[c * TTILE + t4 * 4]) = v;
    }
    // ---- stage rinv (512 floats)
    rinvs[tid]       = rinv_g[tid];
    rinvs[tid + 256] = rinv_g[tid + 256];

    const int tg = tid & 15;   // token group: tokens 4*tg .. 4*tg+3
    const int rg = tid >> 4;   // row group within chunk: rows 4*rg .. 4*rg+3

    float bestv[4] = {-1e30f, -1e30f, -1e30f, -1e30f};
    int   besti[4] = {0, 0, 0, 0};

    for (int chunk = 0; chunk < NCHUNK; ++chunk) {
        __syncthreads();   // previous chunk's ms reads complete
        // ---- stage memory chunk: 64 rows x 128 ch -> ms[row][c] (padded)
        const float* mb = mem + (size_t)(chunk * RCHUNK) * CCH;
        #pragma unroll
        for (int k = 0; k < 8; ++k) {
            int l4 = tid + k * THREADS;        // 0..2047 float4s
            int row = l4 >> 5, c4 = l4 & 31;
            f4 v = *reinterpret_cast<const f4*>(mb + row * CCH + c4 * 4);
            *reinterpret_cast<f4*>(&ms[row * MS_STRIDE + c4 * 4]) = v;
        }
        __syncthreads();

        float acc[4][4];
        #pragma unroll
        for (int t = 0; t < 4; ++t)
            #pragma unroll
            for (int j = 0; j < 4; ++j) acc[t][j] = 0.f;

        // ---- 4-token x 4-row register tile over 128 channels
        #pragma unroll 4
        for (int cq = 0; cq < 32; ++cq) {
            f4 xv[4], mv[4];
            #pragma unroll
            for (int q = 0; q < 4; ++q)   // x for 4 tokens at channel 4cq+q
                xv[q] = *reinterpret_cast<const f4*>(&xs[(cq * 4 + q) * TTILE + tg * 4]);
            #pragma unroll
            for (int j = 0; j < 4; ++j)   // m row 4rg+j, channels 4cq..4cq+3
                mv[j] = *reinterpret_cast<const f4*>(&ms[(rg * 4 + j) * MS_STRIDE + cq * 4]);
            #pragma unroll
            for (int t = 0; t < 4; ++t)
                #pragma unroll
                for (int j = 0; j < 4; ++j) {
                    acc[t][j] = fmaf(xv[0][t], mv[j][0], acc[t][j]);
                    acc[t][j] = fmaf(xv[1][t], mv[j][1], acc[t][j]);
                    acc[t][j] = fmaf(xv[2][t], mv[j][2], acc[t][j]);
                    acc[t][j] = fmaf(xv[3][t], mv[j][3], acc[t][j]);
                }
        }

        // ---- fold chunk into running (max, argmax); rows visited ascending
        const int rowbase = chunk * RCHUNK + rg * 4;
        #pragma unroll
        for (int j = 0; j < 4; ++j) {
            float rv = rinvs[rowbase + j];
            #pragma unroll
            for (int t = 0; t < 4; ++t) {
                float v = acc[t][j] * rv;
                if (v > bestv[t]) { bestv[t] = v; besti[t] = rowbase + j; }
            }
        }
    }

    // ---- cross-rowgroup reduction per token (16 partials each)
    #pragma unroll
    for (int t = 0; t < 4; ++t) {
        redv[(tg * 4 + t) * 16 + rg] = bestv[t];
        redi[(tg * 4 + t) * 16 + rg] = besti[t];
    }
    __syncthreads();
    if (tid < TTILE) {
        const int t = tid;
        float bv = -1e30f; int bi = 0x7fffffff;
        #pragma unroll
        for (int g = 0; g < 16; ++g) {
            float v = redv[t * 16 + g];
            int   i = redi[t * 16 + g];
            if (v > bv || (v == bv && i < bi)) { bv = v; bi = i; }
        }
        // token L2 norm from LDS (conflict-free: stride-1 across lanes)
        float s = 0.f;
        #pragma unroll 8
        for (int c = 0; c < CCH; ++c) { float v = xs[c * TTILE + t]; s += v * v; }
        float xn = sqrtf(s);
        float maxval = bv / fmaxf(xn, 1e-12f);
        fmask[t] = (maxval > 0.8f) ? 1.0f : 0.0f;
        fidx[t]  = bi;
    }
    __syncthreads();

    // ---- output: out[b][c][t0+t] = mask ? memory[idx][c] : 0
    float* ob = out + (size_t)b * CCH * HWTOK + t0;
    #pragma unroll 4
    for (int k = 0; k < 32; ++k) {
        int l = tid + k * THREADS;   // 0..8191
        int c = l >> 6, t = l & 63;
        float val = 0.f;
        if (fmask[t] != 0.f) val = mem[fidx[t] * CCH + c];
        ob[(size_t)c * HWTOK + t] = val;
    }
}

extern "C" void kernel_launch(void* const* d_in, const int* in_sizes, int n_in,
                              void* d_out, int out_size, void* d_ws, size_t ws_size,
                              hipStream_t stream) {
    const float* x   = (const float*)d_in[0];   // [32,128,64,64]
    const float* mem = (const float*)d_in[1];   // [512,128]
    float* out       = (float*)d_out;           // [32,128,64,64]
    float* rinv      = (float*)d_ws;            // 512 floats scratch

    rinv_kernel<<<(MROWS + 63) / 64, 64, 0, stream>>>(mem, rinv);
    hardmem_kernel<<<BATCH * (HWTOK / TTILE), THREADS, 0, stream>>>(x, mem, rinv, out);
}

// Round 2
// 75.582 us; speedup vs baseline: 3.3370x; 3.3370x over previous
//
#include <hip/hip_runtime.h>
#include <math.h>

#define CCH     128
#define HWTOK   4096
#define MROWS   512
#define THREADS 256

using short8  = __attribute__((ext_vector_type(8))) short;
using float16 = __attribute__((ext_vector_type(16))) float;
using f4      = __attribute__((ext_vector_type(4))) float;
using i4      = __attribute__((ext_vector_type(4))) int;

__device__ __forceinline__ unsigned f2bf_rne(float f) {
    unsigned u = __builtin_bit_cast(unsigned, f);
    return (u + 0x7FFFu + ((u >> 16) & 1u)) >> 16;
}

// ---------------------------------------------------------------------------
// Prep: pre-normalized bf16 memory rows as MFMA A-fragments in ws.
// fid = (mt*8 + kstep)*64 + lane, lane = hi*32 + r5:
//   holds memory[mt*32 + r5][kstep*16 + hi*8 + j] * rinv(row), j = 0..7 (bf16)
// so the main kernel's A-frag load is ws + (mt*8+kstep)*64 + lane  (coalesced).
// ---------------------------------------------------------------------------
__global__ __launch_bounds__(256) void frag_kernel(const float* __restrict__ mem,
                                                   i4* __restrict__ wsfrag) {
    int fid   = blockIdx.x * 256 + threadIdx.x;   // 0..8191
    int mt    = fid >> 9;
    int rem   = fid & 511;
    int kstep = rem >> 6;
    int l     = rem & 63;
    int hi    = l >> 5, r5 = l & 31;
    int row   = mt * 32 + r5;
    int k0    = kstep * 16 + hi * 8;

    const float* mr = mem + (size_t)row * CCH;
    float s = 0.f;
    #pragma unroll
    for (int c = 0; c < CCH; c += 4) {
        f4 v = *reinterpret_cast<const f4*>(mr + c);
        s += v.x * v.x + v.y * v.y + v.z * v.z + v.w * v.w;
    }
    float sc = 1.0f / fmaxf(sqrtf(s), 1e-12f);

    unsigned p[4];
    #pragma unroll
    for (int j = 0; j < 4; ++j) {
        unsigned lo = f2bf_rne(mr[k0 + 2 * j]     * sc);
        unsigned hi16 = f2bf_rne(mr[k0 + 2 * j + 1] * sc);
        p[j] = lo | (hi16 << 16);
    }
    i4 o; o.x = p[0]; o.y = p[1]; o.z = p[2]; o.w = p[3];
    wsfrag[fid] = o;
}

// ---------------------------------------------------------------------------
// Main: per wave 64 tokens (2 tiles of 32). B-frags (x, bf16) in registers,
// loop 16 M-tiles of 32 memory rows: 8 A-frag loads + 16 MFMAs + argmax fold.
// ---------------------------------------------------------------------------
__global__ __launch_bounds__(THREADS) void hardmem_mfma(
    const float* __restrict__ x, const float* __restrict__ mem,
    const i4* __restrict__ wsfrag, float* __restrict__ out)
{
    const int tid  = threadIdx.x;
    const int wid  = tid >> 6;
    const int lane = tid & 63;
    const int l5   = lane & 31, hi = lane >> 5;

    const int b   = blockIdx.x >> 4;                       // 16 blocks/batch
    const int tb0 = (blockIdx.x & 15) * 256 + wid * 64;    // wave token base
    const float* xb = x + (size_t)b * CCH * HWTOK;

    // ---- build x B-fragments for 2 token tiles; fp32 sum-of-squares on the fly
    short8 bf[2][8];
    float  s2[2];
    #pragma unroll
    for (int tt = 0; tt < 2; ++tt) {
        const int t = tb0 + tt * 32 + l5;
        const float* xt = xb + t;
        float s = 0.f;
        #pragma unroll
        for (int kstep = 0; kstep < 8; ++kstep) {
            const int c0 = kstep * 16 + hi * 8;
            float v[8];
            #pragma unroll
            for (int j = 0; j < 8; ++j) v[j] = xt[(size_t)(c0 + j) * HWTOK];
            unsigned p[4];
            #pragma unroll
            for (int j = 0; j < 4; ++j) {
                s = fmaf(v[2 * j],     v[2 * j],     s);
                s = fmaf(v[2 * j + 1], v[2 * j + 1], s);
                unsigned u0 = __builtin_bit_cast(unsigned, v[2 * j]);
                unsigned u1 = __builtin_bit_cast(unsigned, v[2 * j + 1]);
                p[j] = (u0 >> 16) | (u1 & 0xFFFF0000u);   // truncate-to-bf16
            }
            i4 pk; pk.x = p[0]; pk.y = p[1]; pk.z = p[2]; pk.w = p[3];
            bf[tt][kstep] = __builtin_bit_cast(short8, pk);
        }
        s2[tt] = s;
    }

    // ---- GEMM + running argmax over 512 memory rows
    float bestv[2] = {-1e30f, -1e30f};
    int   besti[2] = {0, 0};
    const i4* wf = wsfrag + lane;

    for (int mt = 0; mt < 16; ++mt) {
        short8 af[8];
        #pragma unroll
        for (int k = 0; k < 8; ++k)
            af[k] = __builtin_bit_cast(short8, wf[(mt * 8 + k) * 64]);

        float16 acc0, acc1;
        #pragma unroll
        for (int r = 0; r < 16; ++r) { acc0[r] = 0.f; acc1[r] = 0.f; }

        #pragma unroll
        for (int k = 0; k < 8; ++k) {   // two independent chains hide latency
            acc0 = __builtin_amdgcn_mfma_f32_32x32x16_bf16(af[k], bf[0][k], acc0, 0, 0, 0);
            acc1 = __builtin_amdgcn_mfma_f32_32x32x16_bf16(af[k], bf[1][k], acc1, 0, 0, 0);
        }

        const int rbase = mt * 32 + 4 * hi;
        #pragma unroll
        for (int r = 0; r < 16; ++r) {
            // verified C/D map: row = (reg&3) + 8*(reg>>2) + 4*(lane>>5); monotone in r
            const int row = rbase + (r & 3) + 8 * (r >> 2);
            float v0 = acc0[r];
            if (v0 > bestv[0]) { bestv[0] = v0; besti[0] = row; }
            float v1 = acc1[r];
            if (v1 > bestv[1]) { bestv[1] = v1; besti[1] = row; }
        }
    }

    // ---- merge hi halves, threshold, masked gather-store
    float* ob = out + (size_t)b * CCH * HWTOK;
    #pragma unroll
    for (int tt = 0; tt < 2; ++tt) {
        float bv = bestv[tt]; int bi = besti[tt];
        float ov = __shfl_xor(bv, 32);
        int   oi = __shfl_xor(bi, 32);
        if (ov > bv || (ov == bv && oi < bi)) { bv = ov; bi = oi; }
        float n2 = s2[tt] + __shfl_xor(s2[tt], 32);
        float mx = bv / fmaxf(sqrtf(n2), 1e-12f);
        const bool msk = mx > 0.8f;

        const int t = tb0 + tt * 32 + l5;
        const float* mrow = mem + (size_t)bi * CCH;
        if (msk) {
            #pragma unroll 8
            for (int cc = 0; cc < 64; ++cc) {
                int c = hi * 64 + cc;
                ob[(size_t)c * HWTOK + t] = mrow[c];
            }
        } else {
            #pragma unroll 8
            for (int cc = 0; cc < 64; ++cc) {
                int c = hi * 64 + cc;
                ob[(size_t)c * HWTOK + t] = 0.f;
            }
        }
    }
}

// ---------------------------------------------------------------------------
// Fallback (round-1 fp32 kernel) in case ws_size < 128 KB.
// ---------------------------------------------------------------------------
#define TTILE   64
#define RCHUNK  64
#define NCHUNK  (MROWS / RCHUNK)
#define MS_STRIDE 132

__global__ __launch_bounds__(64) void rinv_kernel(const float* __restrict__ mem,
                                                  float* __restrict__ rinv) {
    int r = blockIdx.x * 64 + threadIdx.x;
    if (r >= MROWS) return;
    const float* row = mem + (size_t)r * CCH;
    float s = 0.f;
    #pragma unroll 8
    for (int c = 0; c < CCH; ++c) { float v = row[c]; s += v * v; }
    rinv[r] = 1.0f / fmaxf(sqrtf(s), 1e-12f);
}

__global__ __launch_bounds__(THREADS) void hardmem_kernel(
    const float* __restrict__ x, const float* __restrict__ mem,
    const float* __restrict__ rinv_g, float* __restrict__ out)
{
    __shared__ __align__(16) float xs[CCH * TTILE];
    __shared__ __align__(16) float ms[RCHUNK * MS_STRIDE];
    __shared__ float rinvs[MROWS];
    __shared__ float redv[TTILE * 16];
    __shared__ int   redi[TTILE * 16];
    __shared__ float fmask[TTILE];
    __shared__ int   fidx[TTILE];

    const int tid = threadIdx.x;
    const int b   = blockIdx.x >> 6;
    const int t0  = (blockIdx.x & 63) * TTILE;
    const float* xb = x + (size_t)b * CCH * HWTOK + t0;

    #pragma unroll
    for (int k = 0; k < 8; ++k) {
        int l4 = tid + k * THREADS;
        int c = l4 >> 4, t4 = l4 & 15;
        f4 v = *reinterpret_cast<const f4*>(xb + (size_t)c * HWTOK + t4 * 4);
        *reinterpret_cast<f4*>(&xs[c * TTILE + t4 * 4]) = v;
    }
    rinvs[tid]       = rinv_g[tid];
    rinvs[tid + 256] = rinv_g[tid + 256];

    const int tg = tid & 15;
    const int rg = tid >> 4;
    float bestv[4] = {-1e30f, -1e30f, -1e30f, -1e30f};
    int   besti[4] = {0, 0, 0, 0};

    for (int chunk = 0; chunk < NCHUNK; ++chunk) {
        __syncthreads();
        const float* mb = mem + (size_t)(chunk * RCHUNK) * CCH;
        #pragma unroll
        for (int k = 0; k < 8; ++k) {
            int l4 = tid + k * THREADS;
            int row = l4 >> 5, c4 = l4 & 31;
            f4 v = *reinterpret_cast<const f4*>(mb + row * CCH + c4 * 4);
            *reinterpret_cast<f4*>(&ms[row * MS_STRIDE + c4 * 4]) = v;
        }
        __syncthreads();

        float acc[4][4];
        #pragma unroll
        for (int t = 0; t < 4; ++t)
            #pragma unroll
            for (int j = 0; j < 4; ++j) acc[t][j] = 0.f;

        #pragma unroll 4
        for (int cq = 0; cq < 32; ++cq) {
            f4 xv[4], mv[4];
            #pragma unroll
            for (int q = 0; q < 4; ++q)
                xv[q] = *reinterpret_cast<const f4*>(&xs[(cq * 4 + q) * TTILE + tg * 4]);
            #pragma unroll
            for (int j = 0; j < 4; ++j)
                mv[j] = *reinterpret_cast<const f4*>(&ms[(rg * 4 + j) * MS_STRIDE + cq * 4]);
            #pragma unroll
            for (int t = 0; t < 4; ++t)
                #pragma unroll
                for (int j = 0; j < 4; ++j) {
                    acc[t][j] = fmaf(xv[0][t], mv[j][0], acc[t][j]);
                    acc[t][j] = fmaf(xv[1][t], mv[j][1], acc[t][j]);
                    acc[t][j] = fmaf(xv[2][t], mv[j][2], acc[t][j]);
                    acc[t][j] = fmaf(xv[3][t], mv[j][3], acc[t][j]);
                }
        }

        const int rowbase = chunk * RCHUNK + rg * 4;
        #pragma unroll
        for (int j = 0; j < 4; ++j) {
            float rv = rinvs[rowbase + j];
            #pragma unroll
            for (int t = 0; t < 4; ++t) {
                float v = acc[t][j] * rv;
                if (v > bestv[t]) { bestv[t] = v; besti[t] = rowbase + j; }
            }
        }
    }

    #pragma unroll
    for (int t = 0; t < 4; ++t) {
        redv[(tg * 4 + t) * 16 + rg] = bestv[t];
        redi[(tg * 4 + t) * 16 + rg] = besti[t];
    }
    __syncthreads();
    if (tid < TTILE) {
        const int t = tid;
        float bv = -1e30f; int bi = 0x7fffffff;
        #pragma unroll
        for (int g = 0; g < 16; ++g) {
            float v = redv[t * 16 + g];
            int   i = redi[t * 16 + g];
            if (v > bv || (v == bv && i < bi)) { bv = v; bi = i; }
        }
        float s = 0.f;
        #pragma unroll 8
        for (int c = 0; c < CCH; ++c) { float v = xs[c * TTILE + t]; s += v * v; }
        float maxval = bv / fmaxf(sqrtf(s), 1e-12f);
        fmask[t] = (maxval > 0.8f) ? 1.0f : 0.0f;
        fidx[t]  = bi;
    }
    __syncthreads();

    float* ob = out + (size_t)b * CCH * HWTOK + t0;
    #pragma unroll 4
    for (int k = 0; k < 32; ++k) {
        int l = tid + k * THREADS;
        int c = l >> 6, t = l & 63;
        float val = 0.f;
        if (fmask[t] != 0.f) val = mem[fidx[t] * CCH + c];
        ob[(size_t)c * HWTOK + t] = val;
    }
}

// ---------------------------------------------------------------------------
extern "C" void kernel_launch(void* const* d_in, const int* in_sizes, int n_in,
                              void* d_out, int out_size, void* d_ws, size_t ws_size,
                              hipStream_t stream) {
    const float* x   = (const float*)d_in[0];   // [32,128,64,64]
    const float* mem = (const float*)d_in[1];   // [512,128]
    float* out       = (float*)d_out;

    if (ws_size >= (size_t)(8192 * 16)) {       // 128 KB fragment workspace
        i4* wsfrag = (i4*)d_ws;
        frag_kernel<<<32, 256, 0, stream>>>(mem, wsfrag);
        hardmem_mfma<<<512, THREADS, 0, stream>>>(x, mem, wsfrag, out);
    } else {
        float* rinv = (float*)d_ws;
        rinv_kernel<<<8, 64, 0, stream>>>(mem, rinv);
        hardmem_kernel<<<32 * 64, 256, 0, stream>>>(x, mem, rinv, out);
    }
}

// Round 3
// 63.757 us; speedup vs baseline: 3.9559x; 1.1855x over previous
//
#include <hip/hip_runtime.h>
#include <math.h>

#define CCH     128
#define HWTOK   4096
#define MROWS   512
#define THREADS 256

using short8  = __attribute__((ext_vector_type(8))) short;
using float16 = __attribute__((ext_vector_type(16))) float;
using f4      = __attribute__((ext_vector_type(4))) float;
using i4      = __attribute__((ext_vector_type(4))) int;

__device__ __forceinline__ unsigned f2bf_rne(float f) {
    unsigned u = __builtin_bit_cast(unsigned, f);
    return (u + 0x7FFFu + ((u >> 16) & 1u)) >> 16;
}
__device__ __forceinline__ float fmax3(float a, float b, float c) {
    return fmaxf(fmaxf(a, b), c);   // clang fuses to v_max3_f32
}

// ---------------------------------------------------------------------------
// Prep: pre-normalized bf16 memory rows as MFMA A-fragments in ws.
// fid = (mt*8 + kstep)*64 + lane, lane = hi*32 + r5:
//   holds memory[mt*32 + r5][kstep*16 + hi*8 + j] * rinv(row), j = 0..7 (bf16)
// Main kernel A-frag load: ws + (mt*8+kstep)*64 + lane  -> coalesced 1KB/instr.
// ---------------------------------------------------------------------------
__global__ __launch_bounds__(256) void frag_kernel(const float* __restrict__ mem,
                                                   i4* __restrict__ wsfrag) {
    int fid   = blockIdx.x * 256 + threadIdx.x;   // 0..8191
    int mt    = fid >> 9;
    int rem   = fid & 511;
    int kstep = rem >> 6;
    int l     = rem & 63;
    int hi    = l >> 5, r5 = l & 31;
    int row   = mt * 32 + r5;
    int k0    = kstep * 16 + hi * 8;

    const float* mr = mem + (size_t)row * CCH;
    float s = 0.f;
    #pragma unroll
    for (int c = 0; c < CCH; c += 4) {
        f4 v = *reinterpret_cast<const f4*>(mr + c);
        s += v.x * v.x + v.y * v.y + v.z * v.z + v.w * v.w;
    }
    float sc = 1.0f / fmaxf(sqrtf(s), 1e-12f);

    unsigned p[4];
    #pragma unroll
    for (int j = 0; j < 4; ++j) {
        unsigned lo   = f2bf_rne(mr[k0 + 2 * j]     * sc);
        unsigned hi16 = f2bf_rne(mr[k0 + 2 * j + 1] * sc);
        p[j] = lo | (hi16 << 16);
    }
    i4 o; o.x = p[0]; o.y = p[1]; o.z = p[2]; o.w = p[3];
    wsfrag[fid] = o;
}

// ---------------------------------------------------------------------------
// Main: 1024 blocks x 4 waves; each wave owns 32 tokens (one 32x32 MFMA tile
// column). Hot loop tracks MAX ONLY (no index). Rare slow path (ballot) redoes
// the identical MFMAs with full argmax + first-index tie-break, then gathers.
// ---------------------------------------------------------------------------
__global__ __launch_bounds__(THREADS, 4) void hardmem_mfma(
    const float* __restrict__ x, const float* __restrict__ mem,
    const i4* __restrict__ wsfrag, float* __restrict__ out)
{
    const int tid  = threadIdx.x;
    const int wid  = tid >> 6;
    const int lane = tid & 63;
    const int l5   = lane & 31, hi = lane >> 5;

    const int b   = blockIdx.x >> 5;                       // 32 blocks/batch
    const int tb0 = (blockIdx.x & 31) * 128 + wid * 32;    // wave token base
    const float* xb = x + (size_t)b * CCH * HWTOK;

    // ---- build x B-fragment (token = tb0+l5); fp32 sum-of-squares on the fly
    short8 bf[8];
    float  s2;
    {
        const float* xt = xb + tb0 + l5;
        float s = 0.f;
        #pragma unroll
        for (int kstep = 0; kstep < 8; ++kstep) {
            const int c0 = kstep * 16 + hi * 8;
            float v[8];
            #pragma unroll
            for (int j = 0; j < 8; ++j) v[j] = xt[(size_t)(c0 + j) * HWTOK];
            unsigned p[4];
            #pragma unroll
            for (int j = 0; j < 4; ++j) {
                s = fmaf(v[2 * j],     v[2 * j],     s);
                s = fmaf(v[2 * j + 1], v[2 * j + 1], s);
                unsigned u0 = __builtin_bit_cast(unsigned, v[2 * j]);
                unsigned u1 = __builtin_bit_cast(unsigned, v[2 * j + 1]);
                p[j] = (u0 >> 16) | (u1 & 0xFFFF0000u);   // truncate-to-bf16
            }
            i4 pk; pk.x = p[0]; pk.y = p[1]; pk.z = p[2]; pk.w = p[3];
            bf[kstep] = __builtin_bit_cast(short8, pk);
        }
        s2 = s;
    }

    // ---- hot loop: max-only over 512 rows, A-frags double-buffered from L2
    const i4* wf = wsfrag + lane;
    float bmax = -1e30f;

    short8 afA[8], afB[8];
    #pragma unroll
    for (int k = 0; k < 8; ++k) afA[k] = __builtin_bit_cast(short8, wf[k * 64]);

    for (int mt = 0; mt < 16; mt += 2) {
        #pragma unroll
        for (int k = 0; k < 8; ++k)
            afB[k] = __builtin_bit_cast(short8, wf[((mt + 1) * 8 + k) * 64]);

        float16 acc;
        #pragma unroll
        for (int r = 0; r < 16; ++r) acc[r] = 0.f;
        #pragma unroll
        for (int k = 0; k < 8; ++k)
            acc = __builtin_amdgcn_mfma_f32_32x32x16_bf16(afA[k], bf[k], acc, 0, 0, 0);
        {
            float m0 = fmax3(acc[0], acc[1], acc[2]);
            float m1 = fmax3(acc[3], acc[4], acc[5]);
            float m2 = fmax3(acc[6], acc[7], acc[8]);
            float m3 = fmax3(acc[9], acc[10], acc[11]);
            float m4 = fmax3(acc[12], acc[13], acc[14]);
            bmax = fmaxf(bmax, fmax3(fmax3(m0, m1, m2), fmax3(m3, m4, acc[15]), bmax));
        }

        if (mt + 2 < 16) {
            #pragma unroll
            for (int k = 0; k < 8; ++k)
                afA[k] = __builtin_bit_cast(short8, wf[((mt + 2) * 8 + k) * 64]);
        }

        #pragma unroll
        for (int r = 0; r < 16; ++r) acc[r] = 0.f;
        #pragma unroll
        for (int k = 0; k < 8; ++k)
            acc = __builtin_amdgcn_mfma_f32_32x32x16_bf16(afB[k], bf[k], acc, 0, 0, 0);
        {
            float m0 = fmax3(acc[0], acc[1], acc[2]);
            float m1 = fmax3(acc[3], acc[4], acc[5]);
            float m2 = fmax3(acc[6], acc[7], acc[8]);
            float m3 = fmax3(acc[9], acc[10], acc[11]);
            float m4 = fmax3(acc[12], acc[13], acc[14]);
            bmax = fmaxf(bmax, fmax3(fmax3(m0, m1, m2), fmax3(m3, m4, acc[15]), bmax));
        }
    }

    // ---- threshold: bv/||x|| > 0.8  <=>  bv > 0.8*||x|| (norm > 0)
    bmax = fmaxf(bmax, __shfl_xor(bmax, 32));
    const float n2  = s2 + __shfl_xor(s2, 32);
    const bool  msk = bmax > 0.8f * fmaxf(sqrtf(n2), 1e-12f);

    float* obase = out + (size_t)b * CCH * HWTOK;

    if (__ballot(msk) == 0ULL) {
        // ---- fast path: zero-fill 32 tokens x 128 ch with dwordx4 stores
        float* ob = obase + tb0;
        const int tk = (lane & 7) * 4;       // token group of 4
        const int cb = lane >> 3;            // channel low bits
        f4 z = {0.f, 0.f, 0.f, 0.f};
        #pragma unroll
        for (int cc = 0; cc < 16; ++cc) {
            int c = cc * 8 + cb;
            __builtin_nontemporal_store(z, reinterpret_cast<f4*>(ob + (size_t)c * HWTOK + tk));
        }
    } else {
        // ---- rare slow path: recompute identical accs, track argmax
        float bestv = -1e30f; int besti = 0;
        for (int mt = 0; mt < 16; ++mt) {
            short8 af[8];
            #pragma unroll
            for (int k = 0; k < 8; ++k)
                af[k] = __builtin_bit_cast(short8, wf[(mt * 8 + k) * 64]);
            float16 acc;
            #pragma unroll
            for (int r = 0; r < 16; ++r) acc[r] = 0.f;
            #pragma unroll
            for (int k = 0; k < 8; ++k)
                acc = __builtin_amdgcn_mfma_f32_32x32x16_bf16(af[k], bf[k], acc, 0, 0, 0);
            const int rbase = mt * 32 + 4 * hi;
            #pragma unroll
            for (int r = 0; r < 16; ++r) {
                // verified C/D map: row=(reg&3)+8*(reg>>2)+4*(lane>>5); monotone in r
                const int row = rbase + (r & 3) + 8 * (r >> 2);
                if (acc[r] > bestv) { bestv = acc[r]; besti = row; }
            }
        }
        float ov = __shfl_xor(bestv, 32);
        int   oi = __shfl_xor(besti, 32);
        if (ov > bestv || (ov == bestv && oi < besti)) { bestv = ov; besti = oi; }

        const float* mrow = mem + (size_t)besti * CCH;
        const int t = tb0 + l5;
        #pragma unroll 8
        for (int cc = 0; cc < 64; ++cc) {
            int c = hi * 64 + cc;
            float val = msk ? mrow[c] : 0.f;
            __builtin_nontemporal_store(val, obase + (size_t)c * HWTOK + t);
        }
    }
}

// ---------------------------------------------------------------------------
extern "C" void kernel_launch(void* const* d_in, const int* in_sizes, int n_in,
                              void* d_out, int out_size, void* d_ws, size_t ws_size,
                              hipStream_t stream) {
    const float* x   = (const float*)d_in[0];   // [32,128,64,64]
    const float* mem = (const float*)d_in[1];   // [512,128]
    float* out       = (float*)d_out;
    i4* wsfrag       = (i4*)d_ws;               // 128 KB fragment workspace

    frag_kernel<<<32, 256, 0, stream>>>(mem, wsfrag);
    hardmem_mfma<<<1024, THREADS, 0, stream>>>(x, mem, wsfrag, out);
}